// Round 12
// baseline (535.767 us; speedup 1.0000x reference)
//
#include <hip/hip_runtime.h>

#define NB 8
#define NC 128
#define NM 4096
#define FRAG 512   // shorts per (tile,ks) fragment block: 64 lanes x 8

typedef __attribute__((ext_vector_type(8))) short short8;
typedef __attribute__((ext_vector_type(4))) float floatx4;

#define MFMA(a, b, c) __builtin_amdgcn_mfma_f32_16x16x32_bf16(a, b, c, 0, 0, 0)
#define EXP2F(x) __builtin_amdgcn_exp2f(x)

union S8U { short8 v; uint2 u2[2]; };

__device__ __forceinline__ unsigned pack2bf(float a, float b) {
    unsigned ua = __float_as_uint(a);
    unsigned ub = __float_as_uint(b);
    ua += 0x7fffu + ((ua >> 16) & 1u);
    ub += 0x7fffu + ((ub >> 16) & 1u);
    return (ua >> 16) | (ub & 0xffff0000u);
}

__device__ __forceinline__ unsigned cvt_pk_bf16(float a, float b) {
    unsigned r;
    asm("v_cvt_pk_bf16_f32 %0, %1, %2" : "=v"(r) : "v"(a), "v"(b));
    return r;
}

// QK softmax scale folded into fX: sqrt(2^-3.5 * log2(e)); RS = 1/SF.
__constant__ float SF_C = 0.35712442f;
__constant__ float RS_C = 2.8001530f;

// ---------------------------------------------------------------------------
// FUSED prep (unchanged from round-10 champion).
// ---------------------------------------------------------------------------
__global__ __launch_bounds__(256) void k_prep(
    const float* __restrict__ f, const float* __restrict__ w1,
    unsigned short* __restrict__ fX, unsigned short* __restrict__ gX)
{
    __shared__ __align__(16) char smem[50176];
    float (*Ls)[65] = (float (*)[65])smem;                         // 128x65 f32
    unsigned short (*LsT)[132] =
        (unsigned short (*)[132])(smem + 33280);                   // 64x132 bf16
    unsigned short (*gt2)[72] = (unsigned short (*)[72])smem;      // aliases Ls

    const int tid   = threadIdx.x;
    const int b     = blockIdx.x & 7;
    const int chunk = blockIdx.x >> 3;
    const int m0    = chunk * 64;
    const float* fb = f + (size_t)b * NC * NM;
    #pragma unroll
    for (int k = 0; k < 32; ++k) {
        int idx = tid + k * 256;
        int c = idx >> 6, mm = idx & 63;
        Ls[c][mm] = fb[(size_t)c * NM + m0 + mm];
    }
    __syncthreads();

    const float sf = SF_C;
    const int m  = tid >> 2;
    const int ks = tid & 3;
    const int ch = ks * 32;
    unsigned pk[16];
    #pragma unroll
    for (int i = 0; i < 16; ++i)
        pk[i] = pack2bf(Ls[ch + 2 * i][m] * sf, Ls[ch + 2 * i + 1][m] * sf);
    {
        const int Mg  = m0 + m;
        const int mt  = Mg >> 4;
        const int lmm = Mg & 15;
        unsigned short* dst = fX + ((size_t)b * 256 + mt) * 4 * FRAG + ks * FRAG;
        #pragma unroll
        for (int q = 0; q < 4; ++q)
            *(uint4*)(dst + (q * 16 + lmm) * 8) =
                make_uint4(pk[4 * q], pk[4 * q + 1], pk[4 * q + 2], pk[4 * q + 3]);
    }
    #pragma unroll
    for (int q = 0; q < 4; ++q)
        *(uint4*)&LsT[m][ks * 32 + q * 8] =
            make_uint4(pk[4 * q], pk[4 * q + 1], pk[4 * q + 2], pk[4 * q + 3]);
    __syncthreads();

    const int wv = tid >> 6;
    const int l  = tid & 63;
    const int lm = l & 15;
    const int lq = l >> 4;
    const float rs = RS_C;

    short8 wf2[2][4];
    #pragma unroll
    for (int j = 0; j < 2; ++j) {
        const int o = (wv * 2 + j) * 16 + lm;
        #pragma unroll
        for (int kk = 0; kk < 4; ++kk) {
            const float* wp = w1 + (size_t)o * (2 * NC) + kk * 32 + lq * 8;
            S8U t;
            t.u2[0] = make_uint2(pack2bf(wp[0] * rs, wp[1] * rs),
                                 pack2bf(wp[2] * rs, wp[3] * rs));
            t.u2[1] = make_uint2(pack2bf(wp[4] * rs, wp[5] * rs),
                                 pack2bf(wp[6] * rs, wp[7] * rs));
            wf2[j][kk] = t.v;
        }
    }
    #pragma unroll
    for (int nt = 0; nt < 4; ++nt) {
        short8 af[4];
        #pragma unroll
        for (int kk = 0; kk < 4; ++kk)
            af[kk] = *(const short8*)&LsT[nt * 16 + lm][kk * 32 + lq * 8];
        #pragma unroll
        for (int j = 0; j < 2; ++j) {
            floatx4 D = {0.f, 0.f, 0.f, 0.f};
            #pragma unroll
            for (int kk = 0; kk < 4; ++kk)
                D = MFMA(af[kk], wf2[j][kk], D);
            *(uint2*)&gt2[(wv * 2 + j) * 16 + lm][nt * 16 + lq * 4] =
                make_uint2(pack2bf(D[0], D[1]), pack2bf(D[2], D[3]));
        }
    }
    __syncthreads();

    const int nblk = chunk >> 1;
    const int k2b  = (chunk & 1) * 2;
    #pragma unroll
    for (int j = 0; j < 2; ++j) {
        const int ot = wv * 2 + j;
        #pragma unroll
        for (int k2l = 0; k2l < 2; ++k2l) {
            uint4 v = *(const uint4*)&gt2[ot * 16 + lm][k2l * 32 + lq * 8];
            *(uint4*)(gX + (((size_t)b * 32 + nblk) * 8 + ot) * 4 * FRAG
                      + (k2b + k2l) * FRAG + l * 8) = v;
        }
    }
}

// ---------------------------------------------------------------------------
// Split-n attention pass: grid 1024 = nh(2) x mblk(64) x b(8). Each block is
// the round-10 champion body run for 16 iters over its n-half (disjoint
// ktile/gX ranges -> per-pair traffic unchanged). 4 blocks/CU -> 4 waves/SIMD
// at 128 VGPR: independent out-of-phase blocks fill each other's exp2/ds
// stall holes. Writes unnormalized u + lsum partials to workspace.
// ---------------------------------------------------------------------------
__global__ __launch_bounds__(256, 4) void k_attn_p(
    const unsigned short* __restrict__ fX,
    const unsigned short* __restrict__ gX,
    float* __restrict__ uP, float* __restrict__ lP)
{
    __shared__ __align__(16) char Ps[2][16384];
    __shared__ float lpart[4][64];

    const int tid = threadIdx.x;
    const int w   = tid >> 6;
    const int l   = tid & 63;
    const int lm  = l & 15;
    const int lq  = l >> 4;
    const int s   = blockIdx.x & 511;          // (b, mblk) pair id
    const int b   = s & 7;
    const int m0  = ((s >> 3) & 63) * 64;
    const int nh  = blockIdx.x >> 9;           // n-half

    const int lq0 = lq & 1;
    const int lq1 = lq >> 1;
    const int lm3 = lm >> 3;
    const unsigned Xsw = (unsigned)(((lq1 << 1) | lm3) << 4);
    const unsigned wofsA =
        ((((unsigned)(w >> 1) * 4 * 16) + ((unsigned)(2 * (w & 1) + lq1) * 16)
          + (unsigned)lm) * 16 + (unsigned)(8 * lq0)) ^ Xsw;
    const unsigned rofs = ((unsigned)l * 16) ^ ((((unsigned)l >> 3) & 3u) << 4);

    const unsigned short* fXb = fX + (size_t)b * NM * NC;
    const unsigned short* gXb = gX + (size_t)b * NC * NM;

    short8 qf[4][4];
    {
        const int qt0 = m0 >> 4;
        #pragma unroll
        for (int mt = 0; mt < 4; ++mt)
            #pragma unroll
            for (int ks = 0; ks < 4; ++ks)
                qf[mt][ks] = *(const short8*)
                    (fXb + (size_t)(qt0 + mt) * 4 * FRAG + ks * FRAG + l * 8);
    }

    const unsigned short* kpA = fXb + (size_t)(nh * 128 + w) * 4 * FRAG + l * 8;
    const unsigned short* kpB = fXb + (size_t)(nh * 128 + 4 + w) * 4 * FRAG + l * 8;
    const unsigned short* gp0 = gXb + ((size_t)(nh * 16) * 8 + 2 * w) * 4 * FRAG + l * 8;
    const unsigned short* gp1 = gp0 + 4 * FRAG;

    short8 kfA[4], kfB[4];
    short8 gA0[4], gA1[4], gB0[4], gB1[4];
    #pragma unroll
    for (int ks = 0; ks < 4; ++ks) {
        kfA[ks] = *(const short8*)(kpA + ks * FRAG);
        kfB[ks] = *(const short8*)(kpB + ks * FRAG);
    }
    #pragma unroll
    for (int k2 = 0; k2 < 4; ++k2) {           // gA = gf(0)
        gA0[k2] = *(const short8*)(gp0 + k2 * FRAG);
        gA1[k2] = *(const short8*)(gp1 + k2 * FRAG);
    }

    floatx4 u[4][2];
    float lsum[4] = {0.f, 0.f, 0.f, 0.f};
    #pragma unroll
    for (int mt = 0; mt < 4; ++mt) {
        u[mt][0] = (floatx4){0.f, 0.f, 0.f, 0.f};
        u[mt][1] = (floatx4){0.f, 0.f, 0.f, 0.f};
    }

    // ---- prologue: it = 0 ----
    {
        floatx4 svA[4], svB[4];
        __builtin_amdgcn_s_setprio(1);
        #pragma unroll
        for (int mt = 0; mt < 4; ++mt) {
            floatx4 a = {-24.f, -24.f, -24.f, -24.f};
            floatx4 bb = {-24.f, -24.f, -24.f, -24.f};
            #pragma unroll
            for (int ks = 0; ks < 4; ++ks) {
                a  = MFMA(kfA[ks], qf[mt][ks], a);
                bb = MFMA(kfB[ks], qf[mt][ks], bb);
            }
            svA[mt] = a; svB[mt] = bb;
        }
        __builtin_amdgcn_s_setprio(0);
        kpA += 8 * 4 * FRAG; kpB += 8 * 4 * FRAG;
        #pragma unroll
        for (int ks = 0; ks < 4; ++ks) {
            kfA[ks] = *(const short8*)(kpA + ks * FRAG);
            kfB[ks] = *(const short8*)(kpB + ks * FRAG);
        }
        char* psb = Ps[0];
        #pragma unroll
        for (int mt = 0; mt < 4; ++mt) {
            float pA0 = EXP2F(svA[mt][0]);
            float pA1 = EXP2F(svA[mt][1]);
            float pA2 = EXP2F(svA[mt][2]);
            float pA3 = EXP2F(svA[mt][3]);
            float pB0 = EXP2F(svB[mt][0]);
            float pB1 = EXP2F(svB[mt][1]);
            float pB2 = EXP2F(svB[mt][2]);
            float pB3 = EXP2F(svB[mt][3]);
            lsum[mt] += ((pA0 + pA1) + (pA2 + pA3)) +
                        ((pB0 + pB1) + (pB2 + pB3));
            *(uint2*)(psb + mt * 4096 + wofsA) =
                make_uint2(cvt_pk_bf16(pA0, pA1), cvt_pk_bf16(pA2, pA3));
            *(uint2*)(psb + mt * 4096 + wofsA + 2048) =
                make_uint2(cvt_pk_bf16(pB0, pB1), cvt_pk_bf16(pB2, pB3));
        }
        __syncthreads();
    }

    auto body = [&](char* psW, char* psR,
                    short8 (&gC0)[4], short8 (&gC1)[4],
                    short8 (&gN0)[4], short8 (&gN1)[4], bool loadK) {
        floatx4 svA[4], svB[4];
        __builtin_amdgcn_s_setprio(1);
        #pragma unroll
        for (int mt = 0; mt < 4; ++mt) {
            floatx4 a = {-24.f, -24.f, -24.f, -24.f};
            floatx4 bb = {-24.f, -24.f, -24.f, -24.f};
            #pragma unroll
            for (int ks = 0; ks < 4; ++ks) {
                a  = MFMA(kfA[ks], qf[mt][ks], a);
                bb = MFMA(kfB[ks], qf[mt][ks], bb);
            }
            svA[mt] = a; svB[mt] = bb;
        }
        __builtin_amdgcn_s_setprio(0);
        if (loadK) {
            kpA += 8 * 4 * FRAG; kpB += 8 * 4 * FRAG;
            #pragma unroll
            for (int ks = 0; ks < 4; ++ks) {
                kfA[ks] = *(const short8*)(kpA + ks * FRAG);
                kfB[ks] = *(const short8*)(kpB + ks * FRAG);
            }
        }
        gp0 += 8 * 4 * FRAG; gp1 += 8 * 4 * FRAG;
        #pragma unroll
        for (int k2 = 0; k2 < 4; ++k2) {
            gN0[k2] = *(const short8*)(gp0 + k2 * FRAG);
            gN1[k2] = *(const short8*)(gp1 + k2 * FRAG);
        }
        #pragma unroll
        for (int mt = 0; mt < 4; ++mt) {
            float pA0 = EXP2F(svA[mt][0]);
            float pA1 = EXP2F(svA[mt][1]);
            float pA2 = EXP2F(svA[mt][2]);
            float pA3 = EXP2F(svA[mt][3]);
            float pB0 = EXP2F(svB[mt][0]);
            float pB1 = EXP2F(svB[mt][1]);
            float pB2 = EXP2F(svB[mt][2]);
            float pB3 = EXP2F(svB[mt][3]);
            lsum[mt] += ((pA0 + pA1) + (pA2 + pA3)) +
                        ((pB0 + pB1) + (pB2 + pB3));
            *(uint2*)(psW + mt * 4096 + wofsA) =
                make_uint2(cvt_pk_bf16(pA0, pA1), cvt_pk_bf16(pA2, pA3));
            *(uint2*)(psW + mt * 4096 + wofsA + 2048) =
                make_uint2(cvt_pk_bf16(pB0, pB1), cvt_pk_bf16(pB2, pB3));
        }
        #pragma unroll
        for (int k2 = 0; k2 < 4; ++k2) {
            short8 pf[4];
            #pragma unroll
            for (int mt = 0; mt < 4; ++mt)
                pf[mt] = *(const short8*)(psR + mt * 4096 + k2 * 1024 + rofs);
            __builtin_amdgcn_s_setprio(1);
            #pragma unroll
            for (int mt = 0; mt < 4; ++mt) {
                u[mt][0] = MFMA(pf[mt], gC0[k2], u[mt][0]);
                u[mt][1] = MFMA(pf[mt], gC1[k2], u[mt][1]);
            }
            __builtin_amdgcn_s_setprio(0);
        }
        __syncthreads();
    };

    // it = 1..14 (7 odd/even pairs), then it = 15 (no kf prefetch).
    for (int i = 0; i < 7; ++i) {
        body(Ps[1], Ps[0], gA0, gA1, gB0, gB1, true);
        body(Ps[0], Ps[1], gB0, gB1, gA0, gA1, true);
    }
    body(Ps[1], Ps[0], gA0, gA1, gB0, gB1, false);   // it=15: gB <- gf(15)

    // ---- drain: PV(15) from Ps[1] with gB ----
    #pragma unroll
    for (int k2 = 0; k2 < 4; ++k2) {
        short8 pf[4];
        #pragma unroll
        for (int mt = 0; mt < 4; ++mt)
            pf[mt] = *(const short8*)(Ps[1] + mt * 4096 + k2 * 1024 + rofs);
        __builtin_amdgcn_s_setprio(1);
        #pragma unroll
        for (int mt = 0; mt < 4; ++mt) {
            u[mt][0] = MFMA(pf[mt], gB0[k2], u[mt][0]);
            u[mt][1] = MFMA(pf[mt], gB1[k2], u[mt][1]);
        }
        __builtin_amdgcn_s_setprio(0);
    }

    // ---- partial outputs ----
    #pragma unroll
    for (int mt = 0; mt < 4; ++mt) {
        lsum[mt] += __shfl_xor(lsum[mt], 16);
        lsum[mt] += __shfl_xor(lsum[mt], 32);
    }
    if (lq == 0) {
        #pragma unroll
        for (int mt = 0; mt < 4; ++mt)
            lpart[w][mt * 16 + lm] = lsum[mt];
    }
    // u partial: element (lane l, mt, j, r) = (m = mt*16+lq*4+r, o = w*32+j*16+lm)
    float* ub = uP + ((size_t)s * 2 + nh) * (128 * 64);
    #pragma unroll
    for (int mt = 0; mt < 4; ++mt)
        #pragma unroll
        for (int j = 0; j < 2; ++j)
            *(floatx4*)(ub + (size_t)(w * 32 + j * 16 + lm) * 64
                        + mt * 16 + lq * 4) = u[mt][j];
    __syncthreads();
    if (tid < 64)
        lP[((size_t)s * 2 + nh) * 64 + tid] =
            lpart[0][tid] + lpart[1][tid] + lpart[2][tid] + lpart[3][tid];
}

// ---------------------------------------------------------------------------
// Merge + fused cls head: grid 512 = (b, mblk). Sums the two n-half partials,
// recomputes hacc from fX/w1, applies 1/L, BN, leaky, w2-reduce, writes out.
// ---------------------------------------------------------------------------
__global__ __launch_bounds__(256) void k_merge(
    const unsigned short* __restrict__ fX,
    const float* __restrict__ uP, const float* __restrict__ lP,
    const float* __restrict__ w1,
    const float* __restrict__ b1v, const float* __restrict__ gammav,
    const float* __restrict__ betav, const float* __restrict__ rmeanv,
    const float* __restrict__ rvarv, const float* __restrict__ w2v,
    const float* __restrict__ b2v, float* __restrict__ out)
{
    __shared__ float opart[4][64];
    const int tid = threadIdx.x;
    const int w   = tid >> 6;
    const int l   = tid & 63;
    const int lm  = l & 15;
    const int lq  = l >> 4;
    const int s   = blockIdx.x;
    const int b   = s & 7;
    const int m0  = (s >> 3) * 64;

    const unsigned short* fXb = fX + (size_t)b * NM * NC;
    short8 qf[4][4];
    {
        const int qt0 = m0 >> 4;
        #pragma unroll
        for (int mt = 0; mt < 4; ++mt)
            #pragma unroll
            for (int ks = 0; ks < 4; ++ks)
                qf[mt][ks] = *(const short8*)
                    (fXb + (size_t)(qt0 + mt) * 4 * FRAG + ks * FRAG + l * 8);
    }

    // u = sum of the two n-half partials (per-lane, same addressing as writer)
    floatx4 u[4][2];
    {
        const float* u0 = uP + ((size_t)s * 2 + 0) * (128 * 64);
        const float* u1 = uP + ((size_t)s * 2 + 1) * (128 * 64);
        #pragma unroll
        for (int mt = 0; mt < 4; ++mt)
            #pragma unroll
            for (int j = 0; j < 2; ++j) {
                size_t ofs = (size_t)(w * 32 + j * 16 + lm) * 64 + mt * 16 + lq * 4;
                u[mt][j] = *(const floatx4*)(u0 + ofs) + *(const floatx4*)(u1 + ofs);
            }
    }

    floatx4 hacc[4][2];
    {
        const float rs = RS_C;
        #pragma unroll
        for (int j = 0; j < 2; ++j) {
            int o = w * 32 + j * 16 + lm;
            short8 wf[4];
            #pragma unroll
            for (int ks = 0; ks < 4; ++ks) {
                const float* wp = w1 + (size_t)o * (2 * NC) + NC + ks * 32 + lq * 8;
                S8U t;
                t.u2[0] = make_uint2(pack2bf(wp[0] * rs, wp[1] * rs),
                                     pack2bf(wp[2] * rs, wp[3] * rs));
                t.u2[1] = make_uint2(pack2bf(wp[4] * rs, wp[5] * rs),
                                     pack2bf(wp[6] * rs, wp[7] * rs));
                wf[ks] = t.v;
            }
            #pragma unroll
            for (int mt = 0; mt < 4; ++mt) {
                floatx4 a = {0.f, 0.f, 0.f, 0.f};
                #pragma unroll
                for (int ks = 0; ks < 4; ++ks)
                    a = MFMA(qf[mt][ks], wf[ks], a);
                hacc[mt][j] = a;
            }
        }
    }

    float Abn[2], Dbn[2], W2[2];
    #pragma unroll
    for (int j = 0; j < 2; ++j) {
        int o = w * 32 + j * 16 + lm;
        float Ar = gammav[o] * rsqrtf(rvarv[o] + 1e-5f);
        Abn[j] = Ar;
        Dbn[j] = (b1v[o] - rmeanv[o]) * Ar + betav[o];
        W2[j]  = w2v[o];
    }
    const float* l0 = lP + ((size_t)s * 2 + 0) * 64;
    const float* l1 = lP + ((size_t)s * 2 + 1) * 64;
    float av[16];
    #pragma unroll
    for (int mt = 0; mt < 4; ++mt) {
        float4 La = *(const float4*)&l0[mt * 16 + lq * 4];
        float4 Lb = *(const float4*)&l1[mt * 16 + lq * 4];
        float4 Lt = make_float4(La.x + Lb.x, La.y + Lb.y,
                                La.z + Lb.z, La.w + Lb.w);
        #pragma unroll
        for (int r = 0; r < 4; ++r) {
            float rl = 1.f / ((const float*)&Lt)[r];
            float t0 = Abn[0] * (u[mt][0][r] * rl + hacc[mt][0][r]) + Dbn[0];
            float t1 = Abn[1] * (u[mt][1][r] * rl + hacc[mt][1][r]) + Dbn[1];
            t0 = t0 >= 0.f ? t0 : 0.01f * t0;
            t1 = t1 >= 0.f ? t1 : 0.01f * t1;
            av[mt * 4 + r] = W2[0] * t0 + W2[1] * t1;
        }
    }
    #pragma unroll
    for (int i = 0; i < 16; ++i) {
        av[i] += __shfl_xor(av[i], 1);
        av[i] += __shfl_xor(av[i], 2);
        av[i] += __shfl_xor(av[i], 4);
        av[i] += __shfl_xor(av[i], 8);
    }
    if (lm == 0) {
        #pragma unroll
        for (int mt = 0; mt < 4; ++mt)
            #pragma unroll
            for (int r = 0; r < 4; ++r)
                opart[w][mt * 16 + lq * 4 + r] = av[mt * 4 + r];
    }
    __syncthreads();
    if (tid < 64)
        out[(size_t)b * NM + m0 + tid] =
            b2v[0] + opart[0][tid] + opart[1][tid] + opart[2][tid] + opart[3][tid];
}

// ---------------------------------------------------------------------------
// Fallback: round-10 champion single-pass k_attn (used if ws too small).
// ---------------------------------------------------------------------------
__global__ __launch_bounds__(256, 2) void k_attn(
    const unsigned short* __restrict__ fX,
    const unsigned short* __restrict__ gX,
    const float* __restrict__ w1,
    const float* __restrict__ b1v, const float* __restrict__ gammav,
    const float* __restrict__ betav, const float* __restrict__ rmeanv,
    const float* __restrict__ rvarv, const float* __restrict__ w2v,
    const float* __restrict__ b2v, float* __restrict__ out)
{
    __shared__ __align__(16) char Ps[2][16384];
    __shared__ float lpart[4][64];
    __shared__ float opart[4][64];

    const int tid = threadIdx.x;
    const int w   = tid >> 6;
    const int l   = tid & 63;
    const int lm  = l & 15;
    const int lq  = l >> 4;
    const int b   = blockIdx.x & 7;
    const int m0  = (blockIdx.x >> 3) * 64;

    const int lq0 = lq & 1;
    const int lq1 = lq >> 1;
    const int lm3 = lm >> 3;
    const unsigned Xsw = (unsigned)(((lq1 << 1) | lm3) << 4);
    const unsigned wofsA =
        ((((unsigned)(w >> 1) * 4 * 16) + ((unsigned)(2 * (w & 1) + lq1) * 16)
          + (unsigned)lm) * 16 + (unsigned)(8 * lq0)) ^ Xsw;
    const unsigned rofs = ((unsigned)l * 16) ^ ((((unsigned)l >> 3) & 3u) << 4);

    const unsigned short* fXb = fX + (size_t)b * NM * NC;
    const unsigned short* gXb = gX + (size_t)b * NC * NM;

    short8 qf[4][4];
    {
        const int qt0 = m0 >> 4;
        #pragma unroll
        for (int mt = 0; mt < 4; ++mt)
            #pragma unroll
            for (int ks = 0; ks < 4; ++ks)
                qf[mt][ks] = *(const short8*)
                    (fXb + (size_t)(qt0 + mt) * 4 * FRAG + ks * FRAG + l * 8);
    }

    const unsigned short* kpA = fXb + (size_t)w * 4 * FRAG + l * 8;
    const unsigned short* kpB = fXb + (size_t)(4 + w) * 4 * FRAG + l * 8;
    const unsigned short* gp0 = gXb + (size_t)(2 * w) * 4 * FRAG + l * 8;
    const unsigned short* gp1 = gXb + (size_t)(2 * w + 1) * 4 * FRAG + l * 8;

    short8 kfA[4], kfB[4];
    short8 gA0[4], gA1[4], gB0[4], gB1[4];
    #pragma unroll
    for (int ks = 0; ks < 4; ++ks) {
        kfA[ks] = *(const short8*)(kpA + ks * FRAG);
        kfB[ks] = *(const short8*)(kpB + ks * FRAG);
    }
    #pragma unroll
    for (int k2 = 0; k2 < 4; ++k2) {
        gA0[k2] = *(const short8*)(gp0 + k2 * FRAG);
        gA1[k2] = *(const short8*)(gp1 + k2 * FRAG);
    }

    floatx4 u[4][2];
    float lsum[4] = {0.f, 0.f, 0.f, 0.f};
    #pragma unroll
    for (int mt = 0; mt < 4; ++mt) {
        u[mt][0] = (floatx4){0.f, 0.f, 0.f, 0.f};
        u[mt][1] = (floatx4){0.f, 0.f, 0.f, 0.f};
    }

    {
        floatx4 svA[4], svB[4];
        __builtin_amdgcn_s_setprio(1);
        #pragma unroll
        for (int mt = 0; mt < 4; ++mt) {
            floatx4 a = {-24.f, -24.f, -24.f, -24.f};
            floatx4 bb = {-24.f, -24.f, -24.f, -24.f};
            #pragma unroll
            for (int ks = 0; ks < 4; ++ks) {
                a  = MFMA(kfA[ks], qf[mt][ks], a);
                bb = MFMA(kfB[ks], qf[mt][ks], bb);
            }
            svA[mt] = a; svB[mt] = bb;
        }
        __builtin_amdgcn_s_setprio(0);
        kpA += 8 * 4 * FRAG; kpB += 8 * 4 * FRAG;
        #pragma unroll
        for (int ks = 0; ks < 4; ++ks) {
            kfA[ks] = *(const short8*)(kpA + ks * FRAG);
            kfB[ks] = *(const short8*)(kpB + ks * FRAG);
        }
        char* psb = Ps[0];
        #pragma unroll
        for (int mt = 0; mt < 4; ++mt) {
            float pA0 = EXP2F(svA[mt][0]);
            float pA1 = EXP2F(svA[mt][1]);
            float pA2 = EXP2F(svA[mt][2]);
            float pA3 = EXP2F(svA[mt][3]);
            float pB0 = EXP2F(svB[mt][0]);
            float pB1 = EXP2F(svB[mt][1]);
            float pB2 = EXP2F(svB[mt][2]);
            float pB3 = EXP2F(svB[mt][3]);
            lsum[mt] += ((pA0 + pA1) + (pA2 + pA3)) +
                        ((pB0 + pB1) + (pB2 + pB3));
            *(uint2*)(psb + mt * 4096 + wofsA) =
                make_uint2(cvt_pk_bf16(pA0, pA1), cvt_pk_bf16(pA2, pA3));
            *(uint2*)(psb + mt * 4096 + wofsA + 2048) =
                make_uint2(cvt_pk_bf16(pB0, pB1), cvt_pk_bf16(pB2, pB3));
        }
        __syncthreads();
    }

    auto body = [&](char* psW, char* psR,
                    short8 (&gC0)[4], short8 (&gC1)[4],
                    short8 (&gN0)[4], short8 (&gN1)[4], bool loadK) {
        floatx4 svA[4], svB[4];
        __builtin_amdgcn_s_setprio(1);
        #pragma unroll
        for (int mt = 0; mt < 4; ++mt) {
            floatx4 a = {-24.f, -24.f, -24.f, -24.f};
            floatx4 bb = {-24.f, -24.f, -24.f, -24.f};
            #pragma unroll
            for (int ks = 0; ks < 4; ++ks) {
                a  = MFMA(kfA[ks], qf[mt][ks], a);
                bb = MFMA(kfB[ks], qf[mt][ks], bb);
            }
            svA[mt] = a; svB[mt] = bb;
        }
        __builtin_amdgcn_s_setprio(0);
        if (loadK) {
            kpA += 8 * 4 * FRAG; kpB += 8 * 4 * FRAG;
            #pragma unroll
            for (int ks = 0; ks < 4; ++ks) {
                kfA[ks] = *(const short8*)(kpA + ks * FRAG);
                kfB[ks] = *(const short8*)(kpB + ks * FRAG);
            }
        }
        gp0 += 8 * 4 * FRAG; gp1 += 8 * 4 * FRAG;
        #pragma unroll
        for (int k2 = 0; k2 < 4; ++k2) {
            gN0[k2] = *(const short8*)(gp0 + k2 * FRAG);
            gN1[k2] = *(const short8*)(gp1 + k2 * FRAG);
        }
        #pragma unroll
        for (int mt = 0; mt < 4; ++mt) {
            float pA0 = EXP2F(svA[mt][0]);
            float pA1 = EXP2F(svA[mt][1]);
            float pA2 = EXP2F(svA[mt][2]);
            float pA3 = EXP2F(svA[mt][3]);
            float pB0 = EXP2F(svB[mt][0]);
            float pB1 = EXP2F(svB[mt][1]);
            float pB2 = EXP2F(svB[mt][2]);
            float pB3 = EXP2F(svB[mt][3]);
            lsum[mt] += ((pA0 + pA1) + (pA2 + pA3)) +
                        ((pB0 + pB1) + (pB2 + pB3));
            *(uint2*)(psW + mt * 4096 + wofsA) =
                make_uint2(cvt_pk_bf16(pA0, pA1), cvt_pk_bf16(pA2, pA3));
            *(uint2*)(psW + mt * 4096 + wofsA + 2048) =
                make_uint2(cvt_pk_bf16(pB0, pB1), cvt_pk_bf16(pB2, pB3));
        }
        #pragma unroll
        for (int k2 = 0; k2 < 4; ++k2) {
            short8 pf[4];
            #pragma unroll
            for (int mt = 0; mt < 4; ++mt)
                pf[mt] = *(const short8*)(psR + mt * 4096 + k2 * 1024 + rofs);
            __builtin_amdgcn_s_setprio(1);
            #pragma unroll
            for (int mt = 0; mt < 4; ++mt) {
                u[mt][0] = MFMA(pf[mt], gC0[k2], u[mt][0]);
                u[mt][1] = MFMA(pf[mt], gC1[k2], u[mt][1]);
            }
            __builtin_amdgcn_s_setprio(0);
        }
        __syncthreads();
    };

    for (int i = 0; i < 15; ++i) {
        body(Ps[1], Ps[0], gA0, gA1, gB0, gB1, true);
        body(Ps[0], Ps[1], gB0, gB1, gA0, gA1, true);
    }
    body(Ps[1], Ps[0], gA0, gA1, gB0, gB1, false);

    #pragma unroll
    for (int k2 = 0; k2 < 4; ++k2) {
        short8 pf[4];
        #pragma unroll
        for (int mt = 0; mt < 4; ++mt)
            pf[mt] = *(const short8*)(Ps[1] + mt * 4096 + k2 * 1024 + rofs);
        __builtin_amdgcn_s_setprio(1);
        #pragma unroll
        for (int mt = 0; mt < 4; ++mt) {
            u[mt][0] = MFMA(pf[mt], gB0[k2], u[mt][0]);
            u[mt][1] = MFMA(pf[mt], gB1[k2], u[mt][1]);
        }
        __builtin_amdgcn_s_setprio(0);
    }

    #pragma unroll
    for (int mt = 0; mt < 4; ++mt) {
        lsum[mt] += __shfl_xor(lsum[mt], 16);
        lsum[mt] += __shfl_xor(lsum[mt], 32);
    }
    if (lq == 0) {
        #pragma unroll
        for (int mt = 0; mt < 4; ++mt)
            lpart[w][mt * 16 + lm] = lsum[mt];
    }

    floatx4 hacc[4][2];
    {
        const float rs = RS_C;
        #pragma unroll
        for (int j = 0; j < 2; ++j) {
            int o = w * 32 + j * 16 + lm;
            short8 wf[4];
            #pragma unroll
            for (int ks = 0; ks < 4; ++ks) {
                const float* wp = w1 + (size_t)o * (2 * NC) + NC + ks * 32 + lq * 8;
                S8U t;
                t.u2[0] = make_uint2(pack2bf(wp[0] * rs, wp[1] * rs),
                                     pack2bf(wp[2] * rs, wp[3] * rs));
                t.u2[1] = make_uint2(pack2bf(wp[4] * rs, wp[5] * rs),
                                     pack2bf(wp[6] * rs, wp[7] * rs));
                wf[ks] = t.v;
            }
            #pragma unroll
            for (int mt = 0; mt < 4; ++mt) {
                floatx4 a = {0.f, 0.f, 0.f, 0.f};
                #pragma unroll
                for (int ks = 0; ks < 4; ++ks)
                    a = MFMA(qf[mt][ks], wf[ks], a);
                hacc[mt][j] = a;
            }
        }
    }
    __syncthreads();

    float Abn[2], Dbn[2], W2[2];
    #pragma unroll
    for (int j = 0; j < 2; ++j) {
        int o = w * 32 + j * 16 + lm;
        float Ar = gammav[o] * rsqrtf(rvarv[o] + 1e-5f);
        Abn[j] = Ar;
        Dbn[j] = (b1v[o] - rmeanv[o]) * Ar + betav[o];
        W2[j]  = w2v[o];
    }
    float av[16];
    #pragma unroll
    for (int mt = 0; mt < 4; ++mt) {
        float4 L0 = *(const float4*)&lpart[0][mt * 16 + lq * 4];
        float4 L1 = *(const float4*)&lpart[1][mt * 16 + lq * 4];
        float4 L2 = *(const float4*)&lpart[2][mt * 16 + lq * 4];
        float4 L3 = *(const float4*)&lpart[3][mt * 16 + lq * 4];
        float4 Lt;
        Lt.x = (L0.x + L1.x) + (L2.x + L3.x);
        Lt.y = (L0.y + L1.y) + (L2.y + L3.y);
        Lt.z = (L0.z + L1.z) + (L2.z + L3.z);
        Lt.w = (L0.w + L1.w) + (L2.w + L3.w);
        #pragma unroll
        for (int r = 0; r < 4; ++r) {
            float rl = 1.f / ((const float*)&Lt)[r];
            float t0 = Abn[0] * (u[mt][0][r] * rl + hacc[mt][0][r]) + Dbn[0];
            float t1 = Abn[1] * (u[mt][1][r] * rl + hacc[mt][1][r]) + Dbn[1];
            t0 = t0 >= 0.f ? t0 : 0.01f * t0;
            t1 = t1 >= 0.f ? t1 : 0.01f * t1;
            av[mt * 4 + r] = W2[0] * t0 + W2[1] * t1;
        }
    }
    #pragma unroll
    for (int i = 0; i < 16; ++i) {
        av[i] += __shfl_xor(av[i], 1);
        av[i] += __shfl_xor(av[i], 2);
        av[i] += __shfl_xor(av[i], 4);
        av[i] += __shfl_xor(av[i], 8);
    }
    if (lm == 0) {
        #pragma unroll
        for (int mt = 0; mt < 4; ++mt)
            #pragma unroll
            for (int r = 0; r < 4; ++r)
                opart[w][mt * 16 + lq * 4 + r] = av[mt * 4 + r];
    }
    __syncthreads();
    if (tid < 64)
        out[(size_t)b * NM + m0 + tid] =
            b2v[0] + opart[0][tid] + opart[1][tid] + opart[2][tid] + opart[3][tid];
}

extern "C" void kernel_launch(void* const* d_in, const int* in_sizes, int n_in,
                              void* d_out, int out_size, void* d_ws, size_t ws_size,
                              hipStream_t stream) {
    const float* f     = (const float*)d_in[0];
    const float* w1    = (const float*)d_in[1];
    const float* b1    = (const float*)d_in[2];
    const float* gamma = (const float*)d_in[3];
    const float* beta  = (const float*)d_in[4];
    const float* rmean = (const float*)d_in[5];
    const float* rvar  = (const float*)d_in[6];
    const float* w2    = (const float*)d_in[7];
    const float* b2    = (const float*)d_in[8];
    float* out = (float*)d_out;

    unsigned short* fX = (unsigned short*)d_ws;              // 8 MB bf16 frag-order
    unsigned short* gX = fX + (size_t)NB * NM * NC;          // 8 MB bf16 frag-order
    float* uP = (float*)(gX + (size_t)NB * NM * NC);         // 32 MB u partials
    float* lP = uP + (size_t)1024 * 128 * 64;                // 256 KB l partials

    const size_t ws_needed = (size_t)32 * 1024 * 1024 +
                             (size_t)1024 * 128 * 64 * 4 +
                             (size_t)1024 * 64 * 4;

    hipLaunchKernelGGL(k_prep, dim3(512), dim3(256), 0, stream, f, w1, fX, gX);
    if (ws_size >= ws_needed) {
        hipLaunchKernelGGL(k_attn_p, dim3(1024), dim3(256), 0, stream,
                           fX, gX, uP, lP);
        hipLaunchKernelGGL(k_merge, dim3(512), dim3(256), 0, stream,
                           fX, uP, lP, w1, b1, gamma, beta, rmean, rvar,
                           w2, b2, out);
    } else {
        hipLaunchKernelGGL(k_attn, dim3(512), dim3(256), 0, stream,
                           fX, gX, w1, b1, gamma, beta, rmean, rvar, w2, b2, out);
    }
}

// Round 14
// 153.179 us; speedup vs baseline: 3.4977x; 3.4977x over previous
//
#include <hip/hip_runtime.h>

#define NB 8
#define NC 128
#define NM 4096
#define FRAG 512   // shorts per (tile,ks) fragment block: 64 lanes x 8

typedef __attribute__((ext_vector_type(8))) short short8;
typedef __attribute__((ext_vector_type(4))) float floatx4;

#define MFMA(a, b, c) __builtin_amdgcn_mfma_f32_16x16x32_bf16(a, b, c, 0, 0, 0)
#define EXP2F(x) __builtin_amdgcn_exp2f(x)

union S8U { short8 v; uint2 u2[2]; };

__device__ __forceinline__ unsigned pack2bf(float a, float b) {
    unsigned ua = __float_as_uint(a);
    unsigned ub = __float_as_uint(b);
    ua += 0x7fffu + ((ua >> 16) & 1u);
    ub += 0x7fffu + ((ub >> 16) & 1u);
    return (ua >> 16) | (ub & 0xffff0000u);
}

// Single-instruction packed f32->bf16 (RNE), same rounding as pack2bf.
__device__ __forceinline__ unsigned cvt_pk_bf16(float a, float b) {
    unsigned r;
    asm("v_cvt_pk_bf16_f32 %0, %1, %2" : "=v"(r) : "v"(a), "v"(b));
    return r;
}

// QK softmax scale folded into fX: sqrt(2^-3.5 * log2(e)); RS = 1/SF.
__constant__ float SF_C = 0.35712442f;
__constant__ float RS_C = 2.8001530f;

// ---------------------------------------------------------------------------
// Fragment-order layouts (one contiguous 1024B chunk per wave fragment load):
//   fX[b][mt(256)][ks(4)][lane(64)][8] : lane l=(lq*16+lm) holds
//       f-row (mt*16+lm), cols ks*32+lq*8..+7, scaled by SF, bf16.
//   gX[b][nblk(32)][ot(8)][k2(4)][lane(64)][8] : lane l holds
//       g-row o=ot*16+lm, cols n=nblk*128+k2*32+lq*8..+7, bf16.
// ---------------------------------------------------------------------------

// FUSED prep: per block (b, chunk of 64 indices): stage f -> fX fragments
// (global) + LsT (LDS bf16 transposed copy) -> MFMA g = (w1a*RS).f for the
// same 64 indices as n -> gX fragments.
// chunk <-> (nblk = chunk>>1, k2pair = (chunk&1)*2): exact cover of gX.
// grid 512 = b(8) x chunk(64); 256 threads; ~50 KB LDS -> 2 blocks/CU.
__global__ __launch_bounds__(256) void k_prep(
    const float* __restrict__ f, const float* __restrict__ w1,
    unsigned short* __restrict__ fX, unsigned short* __restrict__ gX)
{
    __shared__ __align__(16) char smem[50176];
    float (*Ls)[65] = (float (*)[65])smem;                         // 128x65 f32
    unsigned short (*LsT)[132] =
        (unsigned short (*)[132])(smem + 33280);                   // 64x132 bf16
    unsigned short (*gt2)[72] = (unsigned short (*)[72])smem;      // aliases Ls

    const int tid   = threadIdx.x;
    const int b     = blockIdx.x & 7;
    const int chunk = blockIdx.x >> 3;
    const int m0    = chunk * 64;
    const float* fb = f + (size_t)b * NC * NM;
    #pragma unroll
    for (int k = 0; k < 32; ++k) {
        int idx = tid + k * 256;
        int c = idx >> 6, mm = idx & 63;
        Ls[c][mm] = fb[(size_t)c * NM + m0 + mm];
    }
    __syncthreads();

    const float sf = SF_C;
    const int m  = tid >> 2;     // 0..63 (local index)
    const int ks = tid & 3;
    const int ch = ks * 32;
    unsigned pk[16];
    #pragma unroll
    for (int i = 0; i < 16; ++i)
        pk[i] = pack2bf(Ls[ch + 2 * i][m] * sf, Ls[ch + 2 * i + 1][m] * sf);
    {   // global fX fragments
        const int Mg  = m0 + m;
        const int mt  = Mg >> 4;
        const int lmm = Mg & 15;
        unsigned short* dst = fX + ((size_t)b * 256 + mt) * 4 * FRAG + ks * FRAG;
        #pragma unroll
        for (int q = 0; q < 4; ++q)
            *(uint4*)(dst + (q * 16 + lmm) * 8) =
                make_uint4(pk[4 * q], pk[4 * q + 1], pk[4 * q + 2], pk[4 * q + 3]);
    }
    // LDS transposed bf16 copy (same packed bits), row m, cols ch..ch+31
    #pragma unroll
    for (int q = 0; q < 4; ++q)
        *(uint4*)&LsT[m][ks * 32 + q * 8] =
            make_uint4(pk[4 * q], pk[4 * q + 1], pk[4 * q + 2], pk[4 * q + 3]);
    __syncthreads();

    // ---- GEMM: g[o][n-local] for n-local = 64 chunk indices ----
    const int wv = tid >> 6;
    const int l  = tid & 63;
    const int lm = l & 15;
    const int lq = l >> 4;
    const float rs = RS_C;

    short8 wf2[2][4];
    #pragma unroll
    for (int j = 0; j < 2; ++j) {
        const int o = (wv * 2 + j) * 16 + lm;
        #pragma unroll
        for (int kk = 0; kk < 4; ++kk) {
            const float* wp = w1 + (size_t)o * (2 * NC) + kk * 32 + lq * 8;
            S8U t;
            t.u2[0] = make_uint2(pack2bf(wp[0] * rs, wp[1] * rs),
                                 pack2bf(wp[2] * rs, wp[3] * rs));
            t.u2[1] = make_uint2(pack2bf(wp[4] * rs, wp[5] * rs),
                                 pack2bf(wp[6] * rs, wp[7] * rs));
            wf2[j][kk] = t.v;
        }
    }
    #pragma unroll
    for (int nt = 0; nt < 4; ++nt) {
        short8 af[4];
        #pragma unroll
        for (int kk = 0; kk < 4; ++kk)
            af[kk] = *(const short8*)&LsT[nt * 16 + lm][kk * 32 + lq * 8];
        #pragma unroll
        for (int j = 0; j < 2; ++j) {
            floatx4 D = {0.f, 0.f, 0.f, 0.f};
            #pragma unroll
            for (int kk = 0; kk < 4; ++kk)
                D = MFMA(af[kk], wf2[j][kk], D);
            *(uint2*)&gt2[(wv * 2 + j) * 16 + lm][nt * 16 + lq * 4] =
                make_uint2(pack2bf(D[0], D[1]), pack2bf(D[2], D[3]));
        }
    }
    __syncthreads();

    // ---- gX fragment store: this chunk's (nblk, k2pair) ----
    const int nblk = chunk >> 1;
    const int k2b  = (chunk & 1) * 2;
    #pragma unroll
    for (int j = 0; j < 2; ++j) {
        const int ot = wv * 2 + j;
        #pragma unroll
        for (int k2l = 0; k2l < 2; ++k2l) {
            uint4 v = *(const uint4*)&gt2[ot * 16 + lm][k2l * 32 + lq * 8];
            *(uint4*)(gX + (((size_t)b * 32 + nblk) * 8 + ot) * 4 * FRAG
                      + (k2b + k2l) * FRAG + l * 8) = v;
        }
    }
}

// ---------------------------------------------------------------------------
// Main: MFMA flash attention + fused cls head. ROUND-10 CHAMPION, verbatim:
// PV-lag-1 pipeline (QK(it) -> Ps[it&1]; PV(it-1) from Ps[(it-1)&1]), one
// __syncthreads per iter, setprio around MFMA clusters, gf register
// ping-pong. grid 512 = b(8) x mblock(64); 4 waves, 2 blocks/CU.
// Survived 7 structural A/Bs (r2,r5,r7,r8,r9,r11,r12/13) — all regressed
// or failed; this ordering/blocking is the measured optimum.
// ---------------------------------------------------------------------------
__global__ __launch_bounds__(256, 2) void k_attn(
    const unsigned short* __restrict__ fX,
    const unsigned short* __restrict__ gX,
    const float* __restrict__ w1,
    const float* __restrict__ b1v, const float* __restrict__ gammav,
    const float* __restrict__ betav, const float* __restrict__ rmeanv,
    const float* __restrict__ rvarv, const float* __restrict__ w2v,
    const float* __restrict__ b2v, float* __restrict__ out)
{
    __shared__ __align__(16) char Ps[2][16384];
    __shared__ float lpart[4][64];
    __shared__ float opart[4][64];

    const int tid = threadIdx.x;
    const int w   = tid >> 6;
    const int l   = tid & 63;
    const int lm  = l & 15;
    const int lq  = l >> 4;
    const int b   = blockIdx.x & 7;
    const int m0  = (blockIdx.x >> 3) * 64;

    // --- Ps addressing (fragment order + XOR swizzle), per-lane constant ---
    const int lq0 = lq & 1;
    const int lq1 = lq >> 1;
    const int lm3 = lm >> 3;
    const unsigned Xsw = (unsigned)(((lq1 << 1) | lm3) << 4);
    const unsigned wofsA =
        ((((unsigned)(w >> 1) * 4 * 16) + ((unsigned)(2 * (w & 1) + lq1) * 16)
          + (unsigned)lm) * 16 + (unsigned)(8 * lq0)) ^ Xsw;
    const unsigned rofs = ((unsigned)l * 16) ^ ((((unsigned)l >> 3) & 3u) << 4);

    const unsigned short* fXb = fX + (size_t)b * NM * NC;
    const unsigned short* gXb = gX + (size_t)b * NC * NM;

    short8 qf[4][4];
    {
        const int qt0 = m0 >> 4;
        #pragma unroll
        for (int mt = 0; mt < 4; ++mt)
            #pragma unroll
            for (int ks = 0; ks < 4; ++ks)
                qf[mt][ks] = *(const short8*)
                    (fXb + (size_t)(qt0 + mt) * 4 * FRAG + ks * FRAG + l * 8);
    }

    const unsigned short* kpA = fXb + (size_t)w * 4 * FRAG + l * 8;
    const unsigned short* kpB = fXb + (size_t)(4 + w) * 4 * FRAG + l * 8;
    const unsigned short* gp0 = gXb + (size_t)(2 * w) * 4 * FRAG + l * 8;
    const unsigned short* gp1 = gXb + (size_t)(2 * w + 1) * 4 * FRAG + l * 8;

    short8 kfA[4], kfB[4];
    short8 gA0[4], gA1[4], gB0[4], gB1[4];
    #pragma unroll
    for (int ks = 0; ks < 4; ++ks) {
        kfA[ks] = *(const short8*)(kpA + ks * FRAG);
        kfB[ks] = *(const short8*)(kpB + ks * FRAG);
    }
    #pragma unroll
    for (int k2 = 0; k2 < 4; ++k2) {           // gA = gf(0)
        gA0[k2] = *(const short8*)(gp0 + k2 * FRAG);
        gA1[k2] = *(const short8*)(gp1 + k2 * FRAG);
    }

    floatx4 u[4][2];
    float lsum[4] = {0.f, 0.f, 0.f, 0.f};
    #pragma unroll
    for (int mt = 0; mt < 4; ++mt) {
        u[mt][0] = (floatx4){0.f, 0.f, 0.f, 0.f};
        u[mt][1] = (floatx4){0.f, 0.f, 0.f, 0.f};
    }

    // ---- prologue: it = 0 -> QK(0), exp2, write Ps[0], barrier ----
    {
        floatx4 svA[4], svB[4];
        __builtin_amdgcn_s_setprio(1);
        #pragma unroll
        for (int mt = 0; mt < 4; ++mt) {
            floatx4 a = {-24.f, -24.f, -24.f, -24.f};
            floatx4 bb = {-24.f, -24.f, -24.f, -24.f};
            #pragma unroll
            for (int ks = 0; ks < 4; ++ks) {
                a  = MFMA(kfA[ks], qf[mt][ks], a);
                bb = MFMA(kfB[ks], qf[mt][ks], bb);
            }
            svA[mt] = a; svB[mt] = bb;
        }
        __builtin_amdgcn_s_setprio(0);
        kpA += 8 * 4 * FRAG; kpB += 8 * 4 * FRAG;   // kf -> kf(1)
        #pragma unroll
        for (int ks = 0; ks < 4; ++ks) {
            kfA[ks] = *(const short8*)(kpA + ks * FRAG);
            kfB[ks] = *(const short8*)(kpB + ks * FRAG);
        }
        char* psb = Ps[0];
        #pragma unroll
        for (int mt = 0; mt < 4; ++mt) {
            float pA0 = EXP2F(svA[mt][0]);
            float pA1 = EXP2F(svA[mt][1]);
            float pA2 = EXP2F(svA[mt][2]);
            float pA3 = EXP2F(svA[mt][3]);
            float pB0 = EXP2F(svB[mt][0]);
            float pB1 = EXP2F(svB[mt][1]);
            float pB2 = EXP2F(svB[mt][2]);
            float pB3 = EXP2F(svB[mt][3]);
            lsum[mt] += ((pA0 + pA1) + (pA2 + pA3)) +
                        ((pB0 + pB1) + (pB2 + pB3));
            *(uint2*)(psb + mt * 4096 + wofsA) =
                make_uint2(cvt_pk_bf16(pA0, pA1), cvt_pk_bf16(pA2, pA3));
            *(uint2*)(psb + mt * 4096 + wofsA + 2048) =
                make_uint2(cvt_pk_bf16(pB0, pB1), cvt_pk_bf16(pB2, pB3));
        }
        __syncthreads();
    }

    // Body for iter IT (1..31): QK(IT) -> Ps[psW]; PV(IT-1) from Ps[psR]
    // with gC; prefetch kf(IT+1) (if LOADK) and gf(IT) into gN.
    auto body = [&](char* psW, char* psR,
                    short8 (&gC0)[4], short8 (&gC1)[4],
                    short8 (&gN0)[4], short8 (&gN1)[4], bool loadK) {
        floatx4 svA[4], svB[4];
        __builtin_amdgcn_s_setprio(1);
        #pragma unroll
        for (int mt = 0; mt < 4; ++mt) {
            floatx4 a = {-24.f, -24.f, -24.f, -24.f};
            floatx4 bb = {-24.f, -24.f, -24.f, -24.f};
            #pragma unroll
            for (int ks = 0; ks < 4; ++ks) {
                a  = MFMA(kfA[ks], qf[mt][ks], a);
                bb = MFMA(kfB[ks], qf[mt][ks], bb);
            }
            svA[mt] = a; svB[mt] = bb;
        }
        __builtin_amdgcn_s_setprio(0);
        if (loadK) {
            kpA += 8 * 4 * FRAG; kpB += 8 * 4 * FRAG;
            #pragma unroll
            for (int ks = 0; ks < 4; ++ks) {
                kfA[ks] = *(const short8*)(kpA + ks * FRAG);
                kfB[ks] = *(const short8*)(kpB + ks * FRAG);
            }
        }
        gp0 += 8 * 4 * FRAG; gp1 += 8 * 4 * FRAG;   // gf(IT)
        #pragma unroll
        for (int k2 = 0; k2 < 4; ++k2) {
            gN0[k2] = *(const short8*)(gp0 + k2 * FRAG);
            gN1[k2] = *(const short8*)(gp1 + k2 * FRAG);
        }
        #pragma unroll
        for (int mt = 0; mt < 4; ++mt) {
            float pA0 = EXP2F(svA[mt][0]);
            float pA1 = EXP2F(svA[mt][1]);
            float pA2 = EXP2F(svA[mt][2]);
            float pA3 = EXP2F(svA[mt][3]);
            float pB0 = EXP2F(svB[mt][0]);
            float pB1 = EXP2F(svB[mt][1]);
            float pB2 = EXP2F(svB[mt][2]);
            float pB3 = EXP2F(svB[mt][3]);
            lsum[mt] += ((pA0 + pA1) + (pA2 + pA3)) +
                        ((pB0 + pB1) + (pB2 + pB3));
            *(uint2*)(psW + mt * 4096 + wofsA) =
                make_uint2(cvt_pk_bf16(pA0, pA1), cvt_pk_bf16(pA2, pA3));
            *(uint2*)(psW + mt * 4096 + wofsA + 2048) =
                make_uint2(cvt_pk_bf16(pB0, pB1), cvt_pk_bf16(pB2, pB3));
        }
        // PV(IT-1): Ps[psR] ready since the previous barrier.
        #pragma unroll
        for (int k2 = 0; k2 < 4; ++k2) {
            short8 pf[4];
            #pragma unroll
            for (int mt = 0; mt < 4; ++mt)
                pf[mt] = *(const short8*)(psR + mt * 4096 + k2 * 1024 + rofs);
            __builtin_amdgcn_s_setprio(1);
            #pragma unroll
            for (int mt = 0; mt < 4; ++mt) {
                u[mt][0] = MFMA(pf[mt], gC0[k2], u[mt][0]);
                u[mt][1] = MFMA(pf[mt], gC1[k2], u[mt][1]);
            }
            __builtin_amdgcn_s_setprio(0);
        }
        __syncthreads();
    };

    // it = 1..30 (15 odd/even pairs), then it = 31 (no kf prefetch).
    for (int i = 0; i < 15; ++i) {
        body(Ps[1], Ps[0], gA0, gA1, gB0, gB1, true);   // odd it: C=gA, N=gB
        body(Ps[0], Ps[1], gB0, gB1, gA0, gA1, true);   // even it: C=gB, N=gA
    }
    body(Ps[1], Ps[0], gA0, gA1, gB0, gB1, false);      // it=31: gB <- gf(31)

    // ---- drain: PV(31) from Ps[1] with gB ----
    #pragma unroll
    for (int k2 = 0; k2 < 4; ++k2) {
        short8 pf[4];
        #pragma unroll
        for (int mt = 0; mt < 4; ++mt)
            pf[mt] = *(const short8*)(Ps[1] + mt * 4096 + k2 * 1024 + rofs);
        __builtin_amdgcn_s_setprio(1);
        #pragma unroll
        for (int mt = 0; mt < 4; ++mt) {
            u[mt][0] = MFMA(pf[mt], gB0[k2], u[mt][0]);
            u[mt][1] = MFMA(pf[mt], gB1[k2], u[mt][1]);
        }
        __builtin_amdgcn_s_setprio(0);
    }

    #pragma unroll
    for (int mt = 0; mt < 4; ++mt) {
        lsum[mt] += __shfl_xor(lsum[mt], 16);
        lsum[mt] += __shfl_xor(lsum[mt], 32);
    }
    if (lq == 0) {
        #pragma unroll
        for (int mt = 0; mt < 4; ++mt)
            lpart[w][mt * 16 + lm] = lsum[mt];
    }

    floatx4 hacc[4][2];
    {
        const float rs = RS_C;
        #pragma unroll
        for (int j = 0; j < 2; ++j) {
            int o = w * 32 + j * 16 + lm;
            short8 wf[4];
            #pragma unroll
            for (int ks = 0; ks < 4; ++ks) {
                const float* wp = w1 + (size_t)o * (2 * NC) + NC + ks * 32 + lq * 8;
                S8U t;
                t.u2[0] = make_uint2(pack2bf(wp[0] * rs, wp[1] * rs),
                                     pack2bf(wp[2] * rs, wp[3] * rs));
                t.u2[1] = make_uint2(pack2bf(wp[4] * rs, wp[5] * rs),
                                     pack2bf(wp[6] * rs, wp[7] * rs));
                wf[ks] = t.v;
            }
            #pragma unroll
            for (int mt = 0; mt < 4; ++mt) {
                floatx4 a = {0.f, 0.f, 0.f, 0.f};
                #pragma unroll
                for (int ks = 0; ks < 4; ++ks)
                    a = MFMA(qf[mt][ks], wf[ks], a);
                hacc[mt][j] = a;
            }
        }
    }
    __syncthreads();

    float Abn[2], Dbn[2], W2[2];
    #pragma unroll
    for (int j = 0; j < 2; ++j) {
        int o = w * 32 + j * 16 + lm;
        float Ar = gammav[o] * rsqrtf(rvarv[o] + 1e-5f);
        Abn[j] = Ar;
        Dbn[j] = (b1v[o] - rmeanv[o]) * Ar + betav[o];
        W2[j]  = w2v[o];
    }
    float av[16];
    #pragma unroll
    for (int mt = 0; mt < 4; ++mt) {
        float4 L0 = *(const float4*)&lpart[0][mt * 16 + lq * 4];
        float4 L1 = *(const float4*)&lpart[1][mt * 16 + lq * 4];
        float4 L2 = *(const float4*)&lpart[2][mt * 16 + lq * 4];
        float4 L3 = *(const float4*)&lpart[3][mt * 16 + lq * 4];
        float4 Lt;
        Lt.x = (L0.x + L1.x) + (L2.x + L3.x);
        Lt.y = (L0.y + L1.y) + (L2.y + L3.y);
        Lt.z = (L0.z + L1.z) + (L2.z + L3.z);
        Lt.w = (L0.w + L1.w) + (L2.w + L3.w);
        #pragma unroll
        for (int r = 0; r < 4; ++r) {
            float rl = 1.f / ((const float*)&Lt)[r];
            float t0 = Abn[0] * (u[mt][0][r] * rl + hacc[mt][0][r]) + Dbn[0];
            float t1 = Abn[1] * (u[mt][1][r] * rl + hacc[mt][1][r]) + Dbn[1];
            t0 = t0 >= 0.f ? t0 : 0.01f * t0;
            t1 = t1 >= 0.f ? t1 : 0.01f * t1;
            av[mt * 4 + r] = W2[0] * t0 + W2[1] * t1;
        }
    }
    #pragma unroll
    for (int i = 0; i < 16; ++i) {
        av[i] += __shfl_xor(av[i], 1);
        av[i] += __shfl_xor(av[i], 2);
        av[i] += __shfl_xor(av[i], 4);
        av[i] += __shfl_xor(av[i], 8);
    }
    if (lm == 0) {
        #pragma unroll
        for (int mt = 0; mt < 4; ++mt)
            #pragma unroll
            for (int r = 0; r < 4; ++r)
                opart[w][mt * 16 + lq * 4 + r] = av[mt * 4 + r];
    }
    __syncthreads();
    if (tid < 64)
        out[(size_t)b * NM + m0 + tid] =
            b2v[0] + opart[0][tid] + opart[1][tid] + opart[2][tid] + opart[3][tid];
}

extern "C" void kernel_launch(void* const* d_in, const int* in_sizes, int n_in,
                              void* d_out, int out_size, void* d_ws, size_t ws_size,
                              hipStream_t stream) {
    const float* f     = (const float*)d_in[0];
    const float* w1    = (const float*)d_in[1];
    const float* b1    = (const float*)d_in[2];
    const float* gamma = (const float*)d_in[3];
    const float* beta  = (const float*)d_in[4];
    const float* rmean = (const float*)d_in[5];
    const float* rvar  = (const float*)d_in[6];
    const float* w2    = (const float*)d_in[7];
    const float* b2    = (const float*)d_in[8];
    float* out = (float*)d_out;

    unsigned short* fX = (unsigned short*)d_ws;              // 8 MB bf16 frag-order
    unsigned short* gX = fX + (size_t)NB * NM * NC;          // 8 MB bf16 frag-order

    hipLaunchKernelGGL(k_prep, dim3(512), dim3(256), 0, stream, f, w1, fX, gX);
    hipLaunchKernelGGL(k_attn, dim3(512), dim3(256), 0, stream,
                       fX, gX, w1, b1, gamma, beta, rmean, rvar, w2, b2, out);
}